// Round 1
// baseline (1915.113 us; speedup 1.0000x reference)
//
#include <hip/hip_runtime.h>
#include <hip/hip_bf16.h>
#include <math.h>

#define FDIM 15
#define FPAD 16
#define NEG_SLOPE 0.2f

// ---- monotone float<->uint encoding for atomicMax on floats ----
__device__ __forceinline__ unsigned fenc(float f) {
  unsigned u = __float_as_uint(f);
  return (u & 0x80000000u) ? ~u : (u | 0x80000000u);
}
__device__ __forceinline__ float fdec(unsigned k) {
  unsigned u = (k & 0x80000000u) ? (k ^ 0x80000000u) : ~k;
  return __uint_as_float(u);
}

// ---- zero fill (avoid hipMemsetAsync inside capture) ----
__global__ void k_zero(float* __restrict__ p, int n) {
  int i = blockIdx.x * blockDim.x + threadIdx.x;
  if (i < n) p[i] = 0.f;
}

// ---- h = in @ W ; as = h @ a_s ; ad = h @ a_d ----
__global__ void k_transform(const float* __restrict__ in, int ld_in,
                            const float* __restrict__ W,
                            const float* __restrict__ a_s,
                            const float* __restrict__ a_d,
                            float* __restrict__ h,
                            float* __restrict__ as_,
                            float* __restrict__ ad_,
                            int n_nodes) {
  __shared__ float Ws[FDIM * FDIM];
  __shared__ float asv[FDIM], adv[FDIM];
  int tid = threadIdx.x;
  if (tid < FDIM * FDIM) Ws[tid] = W[tid];
  if (tid < FDIM) { asv[tid] = a_s[tid]; adv[tid] = a_d[tid]; }
  __syncthreads();
  int n = blockIdx.x * blockDim.x + tid;
  if (n >= n_nodes) return;
  float xin[FDIM];
#pragma unroll
  for (int j = 0; j < FDIM; ++j) xin[j] = in[n * ld_in + j];
  float sa = 0.f, da = 0.f;
#pragma unroll
  for (int o = 0; o < FDIM; ++o) {
    float acc = 0.f;
#pragma unroll
    for (int k = 0; k < FDIM; ++k) acc += xin[k] * Ws[k * FDIM + o];
    h[n * FPAD + o] = acc;
    sa += acc * asv[o];
    da += acc * adv[o];
  }
  h[n * FPAD + FDIM] = 0.f;
  as_[n] = sa;
  ad_[n] = da;
}

// ---- per-edge: e = leaky(as[src]+ad[dst]); store; atomicMax over dst ----
__global__ void k_edge_max(const int* __restrict__ srcI, const int* __restrict__ dstI,
                           const float* __restrict__ as_, const float* __restrict__ ad_,
                           float* __restrict__ ebuf, unsigned* __restrict__ mxk,
                           int n_edges_tot, int n_edges_real) {
  int i = blockIdx.x * blockDim.x + threadIdx.x;
  if (i >= n_edges_tot) return;
  int s, d;
  if (i < n_edges_real) { s = srcI[i]; d = dstI[i]; }
  else { s = d = i - n_edges_real; }  // self loops appended after edges
  float e = as_[s] + ad_[d];
  e = (e > 0.f) ? e : NEG_SLOPE * e;
  ebuf[i] = e;
  atomicMax(&mxk[d], fenc(e));
}

// ---- per-edge: ex = exp(e - mx[dst]); store; atomicAdd den[dst] ----
__global__ void k_edge_expsum(const int* __restrict__ dstI,
                              float* __restrict__ ebuf,
                              const unsigned* __restrict__ mxk,
                              float* __restrict__ den,
                              int n_edges_tot, int n_edges_real) {
  int i = blockIdx.x * blockDim.x + threadIdx.x;
  if (i >= n_edges_tot) return;
  int d = (i < n_edges_real) ? dstI[i] : (i - n_edges_real);
  float ex = expf(ebuf[i] - fdec(mxk[d]));
  ebuf[i] = ex;
  atomicAdd(&den[d], ex);
}

// ---- per-(edge,feature): agg[dst,f] += h[src,f] * ex/(den[dst]+1e-16) ----
__global__ void k_edge_agg(const int* __restrict__ srcI, const int* __restrict__ dstI,
                           const float* __restrict__ ebuf, const float* __restrict__ den,
                           const float* __restrict__ h, float* __restrict__ agg,
                           int n_edges_tot, int n_edges_real) {
  int t = blockIdx.x * blockDim.x + threadIdx.x;
  int i = t >> 4;
  int f = t & 15;
  if (i >= n_edges_tot) return;
  int s, d;
  if (i < n_edges_real) { s = srcI[i]; d = dstI[i]; }
  else { s = d = i - n_edges_real; }
  float alpha = ebuf[i] / (den[d] + 1e-16f);
  if (f < FDIM) atomicAdd(&agg[d * FPAD + f], h[s * FPAD + f] * alpha);
}

// ---- per-node: out = act((agg + cb) @ fW + fb) ----
__global__ void k_ffn(const float* __restrict__ agg,
                      const float* __restrict__ cb,
                      const float* __restrict__ fW,
                      const float* __restrict__ fb,
                      float* __restrict__ outb,
                      int n_nodes, int do_relu) {
  __shared__ float Ws[FDIM * FDIM];
  __shared__ float cbv[FDIM], fbv[FDIM];
  int tid = threadIdx.x;
  if (tid < FDIM * FDIM) Ws[tid] = fW[tid];
  if (tid < FDIM) { cbv[tid] = cb[tid]; fbv[tid] = fb[tid]; }
  __syncthreads();
  int n = blockIdx.x * blockDim.x + tid;
  if (n >= n_nodes) return;
  float xin[FDIM];
#pragma unroll
  for (int j = 0; j < FDIM; ++j) xin[j] = agg[n * FPAD + j] + cbv[j];
#pragma unroll
  for (int o = 0; o < FDIM; ++o) {
    float acc = fbv[o];
#pragma unroll
    for (int k = 0; k < FDIM; ++k) acc += xin[k] * Ws[k * FDIM + o];
    if (do_relu) acc = fmaxf(acc, 0.f);
    outb[n * FPAD + o] = acc;
  }
  outb[n * FPAD + FDIM] = 0.f;
}

// ---- pooling: sum/max/count per graph ----
__global__ void k_pool(const float* __restrict__ hfin, const int* __restrict__ batch,
                       float* __restrict__ sP, unsigned* __restrict__ mpk,
                       float* __restrict__ cnt, int n_nodes) {
  int t = blockIdx.x * blockDim.x + threadIdx.x;
  int n = t >> 4;
  int f = t & 15;
  if (n >= n_nodes) return;
  int g = batch[n];
  if (f < FDIM) {
    float v = hfin[n * FPAD + f];
    atomicAdd(&sP[g * FDIM + f], v);
    atomicMax(&mpk[g * FDIM + f], fenc(v));
  } else {
    atomicAdd(&cnt[g], 1.0f);
  }
}

// ---- small GEMM: C[i,j] = act(sum_k A[i,k]*B[k,j] + bias[j]), one block/row ----
__global__ void k_gemm(const float* __restrict__ A, const float* __restrict__ B,
                       const float* __restrict__ bias, float* __restrict__ C,
                       int K, int Nc, int act) {
  __shared__ float Arow[304];
  int i = blockIdx.x;
  for (int k = threadIdx.x; k < K; k += blockDim.x) Arow[k] = A[i * K + k];
  __syncthreads();
  for (int j = threadIdx.x; j < Nc; j += blockDim.x) {
    float acc = bias[j];
    for (int k = 0; k < K; ++k) acc += Arow[k] * B[k * Nc + j];
    if (act == 1) acc = fmaxf(acc, 0.f);
    else if (act == 2) acc = 1.f / (1.f + expf(-acc));
    C[i * Nc + j] = acc;
  }
}

// ---- head: z=[s,mx,mean,xann] (90) -> relu(z@m1W+m1b) -> sigmoid(@m2W+m2b) ----
__global__ void k_final(const float* __restrict__ sP, const unsigned* __restrict__ mpk,
                        const float* __restrict__ cnt, const float* __restrict__ xann,
                        const float* __restrict__ m1W, const float* __restrict__ m1b,
                        const float* __restrict__ m2W, const float* __restrict__ m2b,
                        float* __restrict__ out) {
  __shared__ float z[90];
  __shared__ float z2[90];
  int g = blockIdx.x;
  int t = threadIdx.x;  // blockDim = 128
  if (t < 15) z[t] = sP[g * FDIM + t];
  else if (t < 30) z[t] = fdec(mpk[g * FDIM + (t - 15)]);
  else if (t < 45) z[t] = sP[g * FDIM + (t - 30)] / fmaxf(cnt[g], 1.0f);
  else if (t < 90) z[t] = xann[g * 45 + (t - 45)];
  __syncthreads();
  if (t < 90) {
    float acc = m1b[t];
    for (int k = 0; k < 90; ++k) acc += z[k] * m1W[k * 90 + t];
    z2[t] = fmaxf(acc, 0.f);
  }
  __syncthreads();
  if (t == 0) {
    float acc = m2b[0];
    for (int k = 0; k < 90; ++k) acc += z2[k] * m2W[k];
    out[g] = 1.f / (1.f + expf(-acc));
  }
}

extern "C" void kernel_launch(void* const* d_in, const int* in_sizes, int n_in,
                              void* d_out, int out_size, void* d_ws, size_t ws_size,
                              hipStream_t stream) {
  const float* x   = (const float*)d_in[0];
  const int* ei    = (const int*)d_in[1];
  const int* batch = (const int*)d_in[2];
  const float* xA  = (const float*)d_in[3];

  const int N = in_sizes[0] / FDIM;
  const int E = in_sizes[1] / 2;
  const int G = in_sizes[3] / 300;
  const int ET = E + N;

  const int* srcI = ei;
  const int* dstI = ei + E;

  // ---- workspace layout (floats). agg/mxk/den contiguous for one zero-fill.
  float* ws = (float*)d_ws;
  size_t off = 0;
  float* h    = ws + off; off += (size_t)N * FPAD;
  float* fout = ws + off; off += (size_t)N * FPAD;
  float* agg  = ws + off; off += (size_t)N * FPAD;   // |
  unsigned* mxk = (unsigned*)(ws + off); off += N;   // | zeroed together (18N)
  float* den  = ws + off; off += N;                  // |
  float* as_  = ws + off; off += N;
  float* ad_  = ws + off; off += N;
  float* ebuf = ws + off; off += (size_t)ET;
  float* sP   = ws + off; off += (size_t)G * FDIM;   // |
  unsigned* mpk = (unsigned*)(ws + off); off += (size_t)G * FDIM;  // | zeroed together (31G)
  float* cnt  = ws + off; off += G;                  // |
  float* a1   = ws + off; off += (size_t)G * 300;
  float* a2   = ws + off; off += (size_t)G * 300;
  float* xann = ws + off; off += (size_t)G * 45;

  const int B = 256;
  const int gN  = (N + B - 1) / B;
  const int gE  = (ET + B - 1) / B;
  const int gEF = (ET * 16 + B - 1) / B;
  const int zeroLayerN = N * FPAD + 2 * N;  // agg + mxk + den
  const int zeroPoolN  = G * (2 * FDIM) + G;

  const float* in_ptr = x;
  int ld_in = FDIM;
  for (int l = 0; l < 3; ++l) {
    const float* cW  = (const float*)d_in[4 + 6 * l];
    const float* cas = (const float*)d_in[5 + 6 * l];
    const float* cad = (const float*)d_in[6 + 6 * l];
    const float* cb  = (const float*)d_in[7 + 6 * l];
    const float* fW  = (const float*)d_in[8 + 6 * l];
    const float* fb  = (const float*)d_in[9 + 6 * l];

    k_transform<<<gN, B, 0, stream>>>(in_ptr, ld_in, cW, cas, cad, h, as_, ad_, N);
    k_zero<<<(zeroLayerN + B - 1) / B, B, 0, stream>>>(agg, zeroLayerN);
    k_edge_max<<<gE, B, 0, stream>>>(srcI, dstI, as_, ad_, ebuf, mxk, ET, E);
    k_edge_expsum<<<gE, B, 0, stream>>>(dstI, ebuf, mxk, den, ET, E);
    k_edge_agg<<<gEF, B, 0, stream>>>(srcI, dstI, ebuf, den, h, agg, ET, E);
    k_ffn<<<gN, B, 0, stream>>>(agg, cb, fW, fb, fout, N, (l < 2) ? 1 : 0);

    in_ptr = fout;
    ld_in = FPAD;
  }

  // ---- pooling ----
  k_zero<<<(zeroPoolN + B - 1) / B, B, 0, stream>>>(sP, zeroPoolN);
  k_pool<<<(N * 16 + B - 1) / B, B, 0, stream>>>(fout, batch, sP, mpk, cnt, N);

  // ---- annotation MLP ----
  const float* m1W = (const float*)d_in[22];
  const float* m1b = (const float*)d_in[23];
  const float* aW1 = (const float*)d_in[24];
  const float* ab1 = (const float*)d_in[25];
  const float* aW2 = (const float*)d_in[26];
  const float* ab2 = (const float*)d_in[27];
  const float* aW3 = (const float*)d_in[28];
  const float* ab3 = (const float*)d_in[29];
  const float* aW4 = (const float*)d_in[30];
  const float* ab4 = (const float*)d_in[31];
  const float* m2W = (const float*)d_in[32];
  const float* m2b = (const float*)d_in[33];

  k_gemm<<<G, 320, 0, stream>>>(xA, aW1, ab1, a1, 300, 300, 1);
  k_gemm<<<G, 320, 0, stream>>>(a1, aW2, ab2, a2, 300, 300, 1);
  k_gemm<<<G, 320, 0, stream>>>(a2, aW3, ab3, a1, 300, 300, 2);
  k_gemm<<<G, 320, 0, stream>>>(a1, aW4, ab4, xann, 300, 45, 0);

  // ---- head ----
  k_final<<<G, 128, 0, stream>>>(sP, mpk, cnt, xann, m1W, m1b, m2W, m2b, (float*)d_out);
}

// Round 2
// 979.991 us; speedup vs baseline: 1.9542x; 1.9542x over previous
//
#include <hip/hip_runtime.h>
#include <hip/hip_bf16.h>
#include <math.h>

#define FDIM 15
#define FPAD 16
#define NEG_SLOPE 0.2f

__device__ __forceinline__ float leaky(float e) {
  return (e > 0.f) ? e : NEG_SLOPE * e;
}

// ---- deg init to 1 (self loop contribution) ----
__global__ void k_fill1(int* __restrict__ p, int n) {
  int i = blockIdx.x * blockDim.x + threadIdx.x;
  if (i < n) p[i] = 1;
}

// ---- degree histogram over real edges ----
__global__ void k_hist(const int* __restrict__ dstI, int* __restrict__ deg, int n_edges) {
  int i = blockIdx.x * blockDim.x + threadIdx.x;
  if (i < n_edges) atomicAdd(&deg[dstI[i]], 1);
}

// ---- scan stage 1: per-block (1024 elems) exclusive scan + block totals ----
__global__ void k_scan1(const int* __restrict__ deg, int* __restrict__ rowptr,
                        int* __restrict__ bsum, int n) {
  __shared__ int s[256];
  int tid = threadIdx.x;
  int base = blockIdx.x * 1024 + tid * 4;
  int v[4]; int t = 0;
#pragma unroll
  for (int k = 0; k < 4; ++k) { v[k] = (base + k < n) ? deg[base + k] : 0; t += v[k]; }
  s[tid] = t;
  __syncthreads();
  for (int off = 1; off < 256; off <<= 1) {
    int add = (tid >= off) ? s[tid - off] : 0;
    __syncthreads();
    s[tid] += add;
    __syncthreads();
  }
  int pre = s[tid] - t;
#pragma unroll
  for (int k = 0; k < 4; ++k) { if (base + k < n) rowptr[base + k] = pre; pre += v[k]; }
  if (tid == 255) bsum[blockIdx.x] = s[255];
}

// ---- scan stage 2: single block exclusive-scans block sums (nb <= 256) ----
__global__ void k_scan2(int* __restrict__ bsum, int nb) {
  __shared__ int s[256];
  int tid = threadIdx.x;
  int v = (tid < nb) ? bsum[tid] : 0;
  s[tid] = v;
  __syncthreads();
  for (int off = 1; off < 256; off <<= 1) {
    int add = (tid >= off) ? s[tid - off] : 0;
    __syncthreads();
    s[tid] += add;
    __syncthreads();
  }
  if (tid < nb) bsum[tid] = s[tid] - v;
}

// ---- scan stage 3: add block offsets, init cursor, set rowptr[N] ----
__global__ void k_scan3(int* __restrict__ rowptr, const int* __restrict__ bsum,
                        int* __restrict__ cursor, int n, int total) {
  int i = blockIdx.x * blockDim.x + threadIdx.x;
  if (i < n) {
    int v = rowptr[i] + bsum[i >> 10];
    rowptr[i] = v;
    cursor[i] = v;
  }
  if (i == 0) rowptr[n] = total;
}

// ---- scatter edges (+self loops) into CSR by dst ----
__global__ void k_scatter(const int* __restrict__ srcI, const int* __restrict__ dstI,
                          int* __restrict__ cursor, int* __restrict__ csr,
                          int n_edges_tot, int n_edges_real) {
  int i = blockIdx.x * blockDim.x + threadIdx.x;
  if (i >= n_edges_tot) return;
  int s, d;
  if (i < n_edges_real) { s = srcI[i]; d = dstI[i]; }
  else { s = d = i - n_edges_real; }
  int j = atomicAdd(&cursor[d], 1);
  csr[j] = s;
}

// ---- h = in @ W ; as = h @ a_s ; ad = h @ a_d ----
__global__ void k_transform(const float* __restrict__ in, int ld_in,
                            const float* __restrict__ W,
                            const float* __restrict__ a_s,
                            const float* __restrict__ a_d,
                            float* __restrict__ h,
                            float* __restrict__ as_,
                            float* __restrict__ ad_,
                            int n_nodes) {
  __shared__ float Ws[FDIM * FDIM];
  __shared__ float asv[FDIM], adv[FDIM];
  int tid = threadIdx.x;
  if (tid < FDIM * FDIM) Ws[tid] = W[tid];
  if (tid < FDIM) { asv[tid] = a_s[tid]; adv[tid] = a_d[tid]; }
  __syncthreads();
  int n = blockIdx.x * blockDim.x + tid;
  if (n >= n_nodes) return;
  float xin[FDIM];
#pragma unroll
  for (int j = 0; j < FDIM; ++j) xin[j] = in[n * ld_in + j];
  float sa = 0.f, da = 0.f;
#pragma unroll
  for (int o = 0; o < FDIM; ++o) {
    float acc = 0.f;
#pragma unroll
    for (int k = 0; k < FDIM; ++k) acc += xin[k] * Ws[k * FDIM + o];
    h[n * FPAD + o] = acc;
    sa += acc * asv[o];
    da += acc * adv[o];
  }
  h[n * FPAD + FDIM] = 0.f;
  as_[n] = sa;
  ad_[n] = da;
}

// ---- fused GAT aggregate + FFN: 16 lanes per dst node, 16 dsts/block ----
__global__ void k_gat(const int* __restrict__ rowptr, const int* __restrict__ csr,
                      const float* __restrict__ as_, const float* __restrict__ ad_,
                      const float* __restrict__ h,
                      const float* __restrict__ cb, const float* __restrict__ fW,
                      const float* __restrict__ fb,
                      float* __restrict__ fout, int n_nodes, int do_relu) {
  __shared__ float Ws[FDIM * FDIM];
  __shared__ float cbv[FDIM], fbv[FDIM];
  __shared__ float aggT[16][16];
  int tid = threadIdx.x;
  if (tid < FDIM * FDIM) Ws[tid] = fW[tid];
  if (tid < FDIM) { cbv[tid] = cb[tid]; fbv[tid] = fb[tid]; }
  __syncthreads();
  int dl = tid >> 4;          // local dst 0..15
  int f  = tid & 15;          // feature lane 0..15
  int d  = blockIdx.x * 16 + dl;
  float val = 0.f;
  if (d < n_nodes) {
    int rs = rowptr[d], re = rowptr[d + 1];
    float adv = ad_[d];
    // pass 1: segment max (lane-strided)
    float m = -INFINITY;
    for (int j = rs + f; j < re; j += 16)
      m = fmaxf(m, leaky(as_[csr[j]] + adv));
#pragma unroll
    for (int k = 8; k; k >>= 1)
      m = fmaxf(m, __shfl_xor(m, k, 16));
    // pass 2: exp-sum + weighted feature aggregation (lane = feature)
    float den = 0.f, acc = 0.f;
    for (int j = rs; j < re; ++j) {
      int s = csr[j];
      float ex = __expf(leaky(as_[s] + adv) - m);
      den += ex;
      acc += h[s * FPAD + f] * ex;
    }
    val = acc / (den + 1e-16f);
  }
  aggT[dl][f] = (f < FDIM) ? (val + cbv[f]) : 0.f;
  __syncthreads();
  // fused FFN: out[d, o] = act(sum_k aggT[dl][k] * fW[k,o] + fb[o])
  if (d < n_nodes) {
    int o = f;
    if (o < FDIM) {
      float acc2 = fbv[o];
#pragma unroll
      for (int k = 0; k < FDIM; ++k) acc2 += aggT[dl][k] * Ws[k * FDIM + o];
      if (do_relu) acc2 = fmaxf(acc2, 0.f);
      fout[d * FPAD + o] = acc2;
    } else {
      fout[d * FPAD + FDIM] = 0.f;
    }
  }
}

// ---- pooling: one block per graph (batch sorted), no atomics ----
__device__ __forceinline__ int lowerb(const int* __restrict__ a, int n, int key) {
  int lo = 0, hi = n;
  while (lo < hi) { int mid = (lo + hi) >> 1; if (a[mid] < key) lo = mid + 1; else hi = mid; }
  return lo;
}

__global__ void k_pool(const float* __restrict__ fout, const int* __restrict__ batch,
                       float* __restrict__ pooled, int n_nodes) {
  __shared__ float ss[256], sm[256];
  int g = blockIdx.x;
  int tid = threadIdx.x;
  int s = lowerb(batch, n_nodes, g);
  int e = lowerb(batch, n_nodes, g + 1);
  int f = tid & 15;
  float sum = 0.f, mx = -INFINITY;
  for (int n = s + (tid >> 4); n < e; n += 16) {
    float v = fout[n * FPAD + f];
    sum += v;
    mx = fmaxf(mx, v);
  }
  ss[tid] = sum; sm[tid] = mx;
  __syncthreads();
  for (int step = 128; step >= 16; step >>= 1) {
    if (tid < step) { ss[tid] += ss[tid + step]; sm[tid] = fmaxf(sm[tid], sm[tid + step]); }
    __syncthreads();
  }
  if (tid < FDIM) {
    float cnt = (float)(e - s);
    float sv = ss[tid];
    pooled[g * 45 + tid] = sv;
    pooled[g * 45 + 15 + tid] = sm[tid];
    pooled[g * 45 + 30 + tid] = sv / fmaxf(cnt, 1.f);
  }
}

// ---- small GEMM: C[i,j] = act(sum_k A[i,k]*B[k,j] + bias[j]), one block/row ----
__global__ void k_gemm(const float* __restrict__ A, const float* __restrict__ B,
                       const float* __restrict__ bias, float* __restrict__ C,
                       int K, int Nc, int act) {
  __shared__ float Arow[304];
  int i = blockIdx.x;
  for (int k = threadIdx.x; k < K; k += blockDim.x) Arow[k] = A[i * K + k];
  __syncthreads();
  for (int j = threadIdx.x; j < Nc; j += blockDim.x) {
    float acc = bias[j];
    for (int k = 0; k < K; ++k) acc += Arow[k] * B[k * Nc + j];
    if (act == 1) acc = fmaxf(acc, 0.f);
    else if (act == 2) acc = 1.f / (1.f + expf(-acc));
    C[i * Nc + j] = acc;
  }
}

// ---- head: z=[pooled,xann] (90) -> relu(z@m1W+m1b) -> sigmoid(@m2W+m2b) ----
__global__ void k_final(const float* __restrict__ pooled, const float* __restrict__ xann,
                        const float* __restrict__ m1W, const float* __restrict__ m1b,
                        const float* __restrict__ m2W, const float* __restrict__ m2b,
                        float* __restrict__ out) {
  __shared__ float z[90];
  __shared__ float z2[90];
  int g = blockIdx.x;
  int t = threadIdx.x;  // blockDim = 128
  if (t < 45) z[t] = pooled[g * 45 + t];
  else if (t < 90) z[t] = xann[g * 45 + (t - 45)];
  __syncthreads();
  if (t < 90) {
    float acc = m1b[t];
    for (int k = 0; k < 90; ++k) acc += z[k] * m1W[k * 90 + t];
    z2[t] = fmaxf(acc, 0.f);
  }
  __syncthreads();
  if (t == 0) {
    float acc = m2b[0];
    for (int k = 0; k < 90; ++k) acc += z2[k] * m2W[k];
    out[g] = 1.f / (1.f + expf(-acc));
  }
}

extern "C" void kernel_launch(void* const* d_in, const int* in_sizes, int n_in,
                              void* d_out, int out_size, void* d_ws, size_t ws_size,
                              hipStream_t stream) {
  const float* x   = (const float*)d_in[0];
  const int* ei    = (const int*)d_in[1];
  const int* batch = (const int*)d_in[2];
  const float* xA  = (const float*)d_in[3];

  const int N = in_sizes[0] / FDIM;
  const int E = in_sizes[1] / 2;
  const int G = in_sizes[3] / 300;
  const int ET = E + N;

  const int* srcI = ei;
  const int* dstI = ei + E;

  // ---- workspace layout (4-byte words) ----
  float* ws = (float*)d_ws;
  size_t off = 0;
  float* h      = ws + off; off += (size_t)N * FPAD;
  float* fout   = ws + off; off += (size_t)N * FPAD;
  float* as_    = ws + off; off += N;
  float* ad_    = ws + off; off += N;
  int*   deg    = (int*)(ws + off); off += N;
  int*   rowptr = (int*)(ws + off); off += N + 1;
  int*   cursor = (int*)(ws + off); off += N;
  int*   bsum   = (int*)(ws + off); off += 256;
  int*   csr    = (int*)(ws + off); off += (size_t)ET;
  float* pooled = ws + off; off += (size_t)G * 45;
  float* a1     = ws + off; off += (size_t)G * 300;
  float* a2     = ws + off; off += (size_t)G * 300;
  float* xann   = ws + off; off += (size_t)G * 45;

  const int B = 256;
  const int gN  = (N + B - 1) / B;
  const int gE  = (E + B - 1) / B;
  const int gET = (ET + B - 1) / B;
  const int nb1 = (N + 1023) / 1024;   // scan stage-1 blocks (<=256)

  // ---- CSR build (once; edges fixed across layers) ----
  k_fill1<<<gN, B, 0, stream>>>(deg, N);
  k_hist<<<gE, B, 0, stream>>>(dstI, deg, E);
  k_scan1<<<nb1, B, 0, stream>>>(deg, rowptr, bsum, N);
  k_scan2<<<1, B, 0, stream>>>(bsum, nb1);
  k_scan3<<<gN, B, 0, stream>>>(rowptr, bsum, cursor, N, ET);
  k_scatter<<<gET, B, 0, stream>>>(srcI, dstI, cursor, csr, ET, E);

  // ---- 3 GAT layers ----
  const float* in_ptr = x;
  int ld_in = FDIM;
  const int gGat = (N + 15) / 16;
  for (int l = 0; l < 3; ++l) {
    const float* cW  = (const float*)d_in[4 + 6 * l];
    const float* cas = (const float*)d_in[5 + 6 * l];
    const float* cad = (const float*)d_in[6 + 6 * l];
    const float* cb  = (const float*)d_in[7 + 6 * l];
    const float* fW  = (const float*)d_in[8 + 6 * l];
    const float* fb  = (const float*)d_in[9 + 6 * l];

    k_transform<<<gN, B, 0, stream>>>(in_ptr, ld_in, cW, cas, cad, h, as_, ad_, N);
    k_gat<<<gGat, B, 0, stream>>>(rowptr, csr, as_, ad_, h, cb, fW, fb, fout,
                                  N, (l < 2) ? 1 : 0);
    in_ptr = fout;
    ld_in = FPAD;
  }

  // ---- pooling (no atomics; batch sorted) ----
  k_pool<<<G, B, 0, stream>>>(fout, batch, pooled, N);

  // ---- annotation MLP ----
  const float* m1W = (const float*)d_in[22];
  const float* m1b = (const float*)d_in[23];
  const float* aW1 = (const float*)d_in[24];
  const float* ab1 = (const float*)d_in[25];
  const float* aW2 = (const float*)d_in[26];
  const float* ab2 = (const float*)d_in[27];
  const float* aW3 = (const float*)d_in[28];
  const float* ab3 = (const float*)d_in[29];
  const float* aW4 = (const float*)d_in[30];
  const float* ab4 = (const float*)d_in[31];
  const float* m2W = (const float*)d_in[32];
  const float* m2b = (const float*)d_in[33];

  k_gemm<<<G, 320, 0, stream>>>(xA, aW1, ab1, a1, 300, 300, 1);
  k_gemm<<<G, 320, 0, stream>>>(a1, aW2, ab2, a2, 300, 300, 1);
  k_gemm<<<G, 320, 0, stream>>>(a2, aW3, ab3, a1, 300, 300, 2);
  k_gemm<<<G, 320, 0, stream>>>(a1, aW4, ab4, xann, 300, 45, 0);

  // ---- head ----
  k_final<<<G, 128, 0, stream>>>(pooled, xann, m1W, m1b, m2W, m2b, (float*)d_out);
}

// Round 3
// 675.443 us; speedup vs baseline: 2.8353x; 1.4509x over previous
//
#include <hip/hip_runtime.h>
#include <hip/hip_bf16.h>
#include <math.h>

#define FDIM 15
#define FPAD 16
#define NEG_SLOPE 0.2f
// dst-buckets of 256 nodes each: bucket = dst >> 8, local = dst & 255
#define BSH 8
#define BWID 256

__device__ __forceinline__ float leaky(float e) {
  return (e > 0.f) ? e : NEG_SLOPE * e;
}

__global__ void k_zero(int* __restrict__ p, int n) {
  int i = blockIdx.x * blockDim.x + threadIdx.x;
  if (i < n) p[i] = 0;
}

// ---- bucket histogram over all edges (incl. self loops) ----
__global__ void k_bhist(const int* __restrict__ dstI, int* __restrict__ bcnt,
                        int n_tot, int n_real, int NB) {
  __shared__ int hist[512];
  int tid = threadIdx.x;
  for (int i = tid; i < NB; i += blockDim.x) hist[i] = 0;
  __syncthreads();
  int stride = gridDim.x * blockDim.x;
  for (int i = blockIdx.x * blockDim.x + tid; i < n_tot; i += stride) {
    int d = (i < n_real) ? dstI[i] : (i - n_real);
    atomicAdd(&hist[d >> BSH], 1);
  }
  __syncthreads();
  for (int i = tid; i < NB; i += blockDim.x)
    if (hist[i]) atomicAdd(&bcnt[i], hist[i]);
}

// ---- exclusive scan of bucket counts (single block, 512 thr) ----
__global__ void k_bscan(const int* __restrict__ bcnt, int* __restrict__ boff,
                        int* __restrict__ bcur, int* __restrict__ rowptr,
                        int NB, int N, int total) {
  __shared__ int s[512];
  int tid = threadIdx.x;
  int v = (tid < NB) ? bcnt[tid] : 0;
  s[tid] = v;
  __syncthreads();
  for (int off = 1; off < 512; off <<= 1) {
    int add = (tid >= off) ? s[tid - off] : 0;
    __syncthreads();
    s[tid] += add;
    __syncthreads();
  }
  if (tid < NB) { int e = s[tid] - v; boff[tid] = e; bcur[tid] = e; }
  if (tid == NB - 1) boff[NB] = s[tid];
  if (tid == 0) rowptr[N] = total;
}

// ---- partition edges into dst-buckets, packed (src<<8 | dst&255) ----
__global__ void k_bpart(const int* __restrict__ srcI, const int* __restrict__ dstI,
                        int* __restrict__ bcur, int* __restrict__ bbuf,
                        int n_tot, int n_real, int NB) {
  __shared__ int hist[512];
  __shared__ int base[512];
  int tid = threadIdx.x;
  for (int i = tid; i < NB; i += blockDim.x) hist[i] = 0;
  __syncthreads();
  int stride = gridDim.x * blockDim.x;
  int g0 = blockIdx.x * blockDim.x + tid;
  for (int i = g0; i < n_tot; i += stride) {
    int d = (i < n_real) ? dstI[i] : (i - n_real);
    atomicAdd(&hist[d >> BSH], 1);
  }
  __syncthreads();
  for (int i = tid; i < NB; i += blockDim.x)
    base[i] = hist[i] ? atomicAdd(&bcur[i], hist[i]) : 0;
  __syncthreads();
  for (int i = tid; i < NB; i += blockDim.x) hist[i] = 0;
  __syncthreads();
  for (int i = g0; i < n_tot; i += stride) {
    int s, d;
    if (i < n_real) { s = srcI[i]; d = dstI[i]; }
    else { s = d = i - n_real; }
    int b = d >> BSH;
    int p = base[b] + atomicAdd(&hist[b], 1);
    bbuf[p] = (s << BSH) | (d & (BWID - 1));
  }
}

// ---- per-bucket: per-dst hist -> scan -> rowptr + csr scatter (L2-local) ----
__global__ void k_bbuild(const int* __restrict__ boff, const int* __restrict__ bbuf,
                         int* __restrict__ rowptr, int* __restrict__ csr, int N) {
  __shared__ int hist[BWID];
  __shared__ int sc[BWID];
  int b = blockIdx.x;
  int tid = threadIdx.x;  // 256
  int base_dst = b << BSH;
  int nd = min(BWID, N - base_dst);
  int s0 = boff[b], s1 = boff[b + 1];
  hist[tid] = 0;
  __syncthreads();
  for (int j = s0 + tid; j < s1; j += BWID)
    atomicAdd(&hist[bbuf[j] & (BWID - 1)], 1);
  __syncthreads();
  int v = hist[tid];
  sc[tid] = v;
  __syncthreads();
  for (int off = 1; off < BWID; off <<= 1) {
    int add = (tid >= off) ? sc[tid - off] : 0;
    __syncthreads();
    sc[tid] += add;
    __syncthreads();
  }
  int excl = sc[tid] - v;
  if (tid < nd) rowptr[base_dst + tid] = s0 + excl;
  __syncthreads();
  hist[tid] = excl;
  __syncthreads();
  for (int j = s0 + tid; j < s1; j += BWID) {
    int e = bbuf[j];
    int dl = e & (BWID - 1);
    int p = s0 + atomicAdd(&hist[dl], 1);
    csr[p] = e >> BSH;
  }
}

// ---- h = in @ W ; as = h @ a_s ; ad = h @ a_d ----
__global__ void k_transform(const float* __restrict__ in, int ld_in,
                            const float* __restrict__ W,
                            const float* __restrict__ a_s,
                            const float* __restrict__ a_d,
                            float* __restrict__ h,
                            float* __restrict__ as_,
                            float* __restrict__ ad_,
                            int n_nodes) {
  __shared__ float Ws[FDIM * FDIM];
  __shared__ float asv[FDIM], adv[FDIM];
  int tid = threadIdx.x;
  if (tid < FDIM * FDIM) Ws[tid] = W[tid];
  if (tid < FDIM) { asv[tid] = a_s[tid]; adv[tid] = a_d[tid]; }
  __syncthreads();
  int n = blockIdx.x * blockDim.x + tid;
  if (n >= n_nodes) return;
  float xin[FDIM];
#pragma unroll
  for (int j = 0; j < FDIM; ++j) xin[j] = in[n * ld_in + j];
  float sa = 0.f, da = 0.f;
#pragma unroll
  for (int o = 0; o < FDIM; ++o) {
    float acc = 0.f;
#pragma unroll
    for (int k = 0; k < FDIM; ++k) acc += xin[k] * Ws[k * FDIM + o];
    h[n * FPAD + o] = acc;
    sa += acc * asv[o];
    da += acc * adv[o];
  }
  h[n * FPAD + FDIM] = 0.f;
  as_[n] = sa;
  ad_[n] = da;
}

// ---- fused GAT aggregate + FFN: one-pass online softmax, 16 lanes/dst ----
__global__ void k_gat(const int* __restrict__ rowptr, const int* __restrict__ csr,
                      const float* __restrict__ as_, const float* __restrict__ ad_,
                      const float* __restrict__ h,
                      const float* __restrict__ cb, const float* __restrict__ fW,
                      const float* __restrict__ fb,
                      float* __restrict__ fout, int n_nodes, int do_relu) {
  __shared__ float Ws[FDIM * FDIM];
  __shared__ float cbv[FDIM], fbv[FDIM];
  __shared__ float aggT[16][16];
  int tid = threadIdx.x;
  if (tid < FDIM * FDIM) Ws[tid] = fW[tid];
  if (tid < FDIM) { cbv[tid] = cb[tid]; fbv[tid] = fb[tid]; }
  __syncthreads();
  int dl = tid >> 4;          // local dst 0..15
  int f  = tid & 15;          // feature lane 0..15
  int d  = blockIdx.x * 16 + dl;
  float val = 0.f;
  if (d < n_nodes) {
    int rs = rowptr[d], re = rowptr[d + 1];
    float adv = ad_[d];
    float m = -INFINITY, den = 0.f, acc = 0.f;
    for (int j = rs; j < re; ++j) {
      int s = csr[j];
      float e = leaky(as_[s] + adv);
      float hv = h[s * FPAD + f];
      if (e <= m) {
        float ex = __expf(e - m);
        den += ex;
        acc += hv * ex;
      } else {
        float sc2 = __expf(m - e);   // first iter: exp(-inf)=0
        den = den * sc2 + 1.f;
        acc = acc * sc2 + hv;
        m = e;
      }
    }
    val = acc / (den + 1e-16f);
  }
  aggT[dl][f] = (f < FDIM) ? (val + cbv[f]) : 0.f;
  __syncthreads();
  if (d < n_nodes) {
    int o = f;
    if (o < FDIM) {
      float acc2 = fbv[o];
#pragma unroll
      for (int k = 0; k < FDIM; ++k) acc2 += aggT[dl][k] * Ws[k * FDIM + o];
      if (do_relu) acc2 = fmaxf(acc2, 0.f);
      fout[d * FPAD + o] = acc2;
    } else {
      fout[d * FPAD + FDIM] = 0.f;
    }
  }
}

// ---- pooling: one block per graph (batch sorted), no atomics ----
__device__ __forceinline__ int lowerb(const int* __restrict__ a, int n, int key) {
  int lo = 0, hi = n;
  while (lo < hi) { int mid = (lo + hi) >> 1; if (a[mid] < key) lo = mid + 1; else hi = mid; }
  return lo;
}

__global__ void k_pool(const float* __restrict__ fout, const int* __restrict__ batch,
                       float* __restrict__ pooled, int n_nodes) {
  __shared__ float ss[256], sm[256];
  int g = blockIdx.x;
  int tid = threadIdx.x;
  int s = lowerb(batch, n_nodes, g);
  int e = lowerb(batch, n_nodes, g + 1);
  int f = tid & 15;
  float sum = 0.f, mx = -INFINITY;
  for (int n = s + (tid >> 4); n < e; n += 16) {
    float v = fout[n * FPAD + f];
    sum += v;
    mx = fmaxf(mx, v);
  }
  ss[tid] = sum; sm[tid] = mx;
  __syncthreads();
  for (int step = 128; step >= 16; step >>= 1) {
    if (tid < step) { ss[tid] += ss[tid + step]; sm[tid] = fmaxf(sm[tid], sm[tid + step]); }
    __syncthreads();
  }
  if (tid < FDIM) {
    float cnt = (float)(e - s);
    float sv = ss[tid];
    pooled[g * 45 + tid] = sv;
    pooled[g * 45 + 15 + tid] = sm[tid];
    pooled[g * 45 + 30 + tid] = sv / fmaxf(cnt, 1.f);
  }
}

// ---- small GEMM: C[i,j] = act(sum_k A[i,k]*B[k,j] + bias[j]) ----
__global__ void k_gemm(const float* __restrict__ A, const float* __restrict__ B,
                       const float* __restrict__ bias, float* __restrict__ C,
                       int K, int Nc, int act) {
  __shared__ float Arow[304];
  int i = blockIdx.x;
  for (int k = threadIdx.x; k < K; k += blockDim.x) Arow[k] = A[i * K + k];
  __syncthreads();
  for (int j = threadIdx.x; j < Nc; j += blockDim.x) {
    float acc = bias[j];
    for (int k = 0; k < K; ++k) acc += Arow[k] * B[k * Nc + j];
    if (act == 1) acc = fmaxf(acc, 0.f);
    else if (act == 2) acc = 1.f / (1.f + expf(-acc));
    C[i * Nc + j] = acc;
  }
}

// ---- head ----
__global__ void k_final(const float* __restrict__ pooled, const float* __restrict__ xann,
                        const float* __restrict__ m1W, const float* __restrict__ m1b,
                        const float* __restrict__ m2W, const float* __restrict__ m2b,
                        float* __restrict__ out) {
  __shared__ float z[90];
  __shared__ float z2[90];
  int g = blockIdx.x;
  int t = threadIdx.x;  // 128
  if (t < 45) z[t] = pooled[g * 45 + t];
  else if (t < 90) z[t] = xann[g * 45 + (t - 45)];
  __syncthreads();
  if (t < 90) {
    float acc = m1b[t];
    for (int k = 0; k < 90; ++k) acc += z[k] * m1W[k * 90 + t];
    z2[t] = fmaxf(acc, 0.f);
  }
  __syncthreads();
  if (t == 0) {
    float acc = m2b[0];
    for (int k = 0; k < 90; ++k) acc += z2[k] * m2W[k];
    out[g] = 1.f / (1.f + expf(-acc));
  }
}

extern "C" void kernel_launch(void* const* d_in, const int* in_sizes, int n_in,
                              void* d_out, int out_size, void* d_ws, size_t ws_size,
                              hipStream_t stream) {
  const float* x   = (const float*)d_in[0];
  const int* ei    = (const int*)d_in[1];
  const int* batch = (const int*)d_in[2];
  const float* xA  = (const float*)d_in[3];

  const int N = in_sizes[0] / FDIM;
  const int E = in_sizes[1] / 2;
  const int G = in_sizes[3] / 300;
  const int ET = E + N;
  const int NB = (N + BWID - 1) >> BSH;   // dst buckets (<=512 for N<=131072)

  const int* srcI = ei;
  const int* dstI = ei + E;

  // ---- workspace layout (4-byte words) ----
  // bbuf (build phase) overlays h/fout/as_/ad_ (layer phase) — never live together.
  float* ws = (float*)d_ws;
  size_t uSize = (size_t)(34 * N) > (size_t)ET ? (size_t)(34 * N) : (size_t)ET;
  size_t off = 0;
  int*   bbuf   = (int*)(ws + off);
  float* h      = ws + off;
  float* fout   = ws + off + (size_t)16 * N;
  float* as_    = ws + off + (size_t)32 * N;
  float* ad_    = ws + off + (size_t)33 * N;
  off += uSize;
  int*   rowptr = (int*)(ws + off); off += N + 1;
  int*   csr    = (int*)(ws + off); off += (size_t)ET;
  int*   bcnt   = (int*)(ws + off); off += 516;
  int*   boff   = (int*)(ws + off); off += 516;
  int*   bcur   = (int*)(ws + off); off += 516;
  float* pooled = ws + off; off += (size_t)G * 45;
  float* a1     = ws + off; off += (size_t)G * 300;
  float* a2     = ws + off; off += (size_t)G * 300;
  float* xann   = ws + off; off += (size_t)G * 45;

  const int B = 256;
  const int gN = (N + B - 1) / B;

  // ---- bucketed CSR build ----
  k_zero<<<(NB + B - 1) / B, B, 0, stream>>>(bcnt, NB);
  k_bhist<<<256, B, 0, stream>>>(dstI, bcnt, ET, E, NB);
  k_bscan<<<1, 512, 0, stream>>>(bcnt, boff, bcur, rowptr, NB, N, ET);
  k_bpart<<<256, B, 0, stream>>>(srcI, dstI, bcur, bbuf, ET, E, NB);
  k_bbuild<<<NB, BWID, 0, stream>>>(boff, bbuf, rowptr, csr, N);

  // ---- 3 GAT layers ----
  const float* in_ptr = x;
  int ld_in = FDIM;
  const int gGat = (N + 15) / 16;
  for (int l = 0; l < 3; ++l) {
    const float* cW  = (const float*)d_in[4 + 6 * l];
    const float* cas = (const float*)d_in[5 + 6 * l];
    const float* cad = (const float*)d_in[6 + 6 * l];
    const float* cb  = (const float*)d_in[7 + 6 * l];
    const float* fW  = (const float*)d_in[8 + 6 * l];
    const float* fb  = (const float*)d_in[9 + 6 * l];

    k_transform<<<gN, B, 0, stream>>>(in_ptr, ld_in, cW, cas, cad, h, as_, ad_, N);
    k_gat<<<gGat, B, 0, stream>>>(rowptr, csr, as_, ad_, h, cb, fW, fb, fout,
                                  N, (l < 2) ? 1 : 0);
    in_ptr = fout;
    ld_in = FPAD;
  }

  // ---- pooling ----
  k_pool<<<G, B, 0, stream>>>(fout, batch, pooled, N);

  // ---- annotation MLP ----
  const float* m1W = (const float*)d_in[22];
  const float* m1b = (const float*)d_in[23];
  const float* aW1 = (const float*)d_in[24];
  const float* ab1 = (const float*)d_in[25];
  const float* aW2 = (const float*)d_in[26];
  const float* ab2 = (const float*)d_in[27];
  const float* aW3 = (const float*)d_in[28];
  const float* ab3 = (const float*)d_in[29];
  const float* aW4 = (const float*)d_in[30];
  const float* ab4 = (const float*)d_in[31];
  const float* m2W = (const float*)d_in[32];
  const float* m2b = (const float*)d_in[33];

  k_gemm<<<G, 320, 0, stream>>>(xA, aW1, ab1, a1, 300, 300, 1);
  k_gemm<<<G, 320, 0, stream>>>(a1, aW2, ab2, a2, 300, 300, 1);
  k_gemm<<<G, 320, 0, stream>>>(a2, aW3, ab3, a1, 300, 300, 2);
  k_gemm<<<G, 320, 0, stream>>>(a1, aW4, ab4, xann, 300, 45, 0);

  // ---- head ----
  k_final<<<G, 128, 0, stream>>>(pooled, xann, m1W, m1b, m2W, m2b, (float*)d_out);
}

// Round 4
// 503.831 us; speedup vs baseline: 3.8011x; 1.3406x over previous
//
#include <hip/hip_runtime.h>
#include <hip/hip_bf16.h>
#include <math.h>

#define FDIM 15
#define FPAD 16
#define NEG_SLOPE 0.2f
// dst-buckets of 256 nodes each: bucket = dst >> 8, local = dst & 255
#define BSH 8
#define BWID 256

typedef _Float16 half_t;

__device__ __forceinline__ float leaky(float e) {
  return (e > 0.f) ? e : NEG_SLOPE * e;
}

__global__ void k_zero(int* __restrict__ p, int n) {
  int i = blockIdx.x * blockDim.x + threadIdx.x;
  if (i < n) p[i] = 0;
}

// ---- bucket histogram over all edges (incl. self loops) ----
__global__ void k_bhist(const int* __restrict__ dstI, int* __restrict__ bcnt,
                        int n_tot, int n_real, int NB) {
  __shared__ int hist[512];
  int tid = threadIdx.x;
  for (int i = tid; i < NB; i += blockDim.x) hist[i] = 0;
  __syncthreads();
  int stride = gridDim.x * blockDim.x;
  for (int i = blockIdx.x * blockDim.x + tid; i < n_tot; i += stride) {
    int d = (i < n_real) ? dstI[i] : (i - n_real);
    atomicAdd(&hist[d >> BSH], 1);
  }
  __syncthreads();
  for (int i = tid; i < NB; i += blockDim.x)
    if (hist[i]) atomicAdd(&bcnt[i], hist[i]);
}

// ---- exclusive scan of bucket counts (single block, 512 thr) ----
__global__ void k_bscan(const int* __restrict__ bcnt, int* __restrict__ boff,
                        int* __restrict__ bcur, int* __restrict__ rowptr,
                        int NB, int N, int total) {
  __shared__ int s[512];
  int tid = threadIdx.x;
  int v = (tid < NB) ? bcnt[tid] : 0;
  s[tid] = v;
  __syncthreads();
  for (int off = 1; off < 512; off <<= 1) {
    int add = (tid >= off) ? s[tid - off] : 0;
    __syncthreads();
    s[tid] += add;
    __syncthreads();
  }
  if (tid < NB) { int e = s[tid] - v; boff[tid] = e; bcur[tid] = e; }
  if (tid == NB - 1) boff[NB] = s[tid];
  if (tid == 0) rowptr[N] = total;
}

// ---- partition edges into dst-buckets, packed (src<<8 | dst&255) ----
__global__ void k_bpart(const int* __restrict__ srcI, const int* __restrict__ dstI,
                        int* __restrict__ bcur, int* __restrict__ bbuf,
                        int n_tot, int n_real, int NB) {
  __shared__ int hist[512];
  __shared__ int base[512];
  int tid = threadIdx.x;
  for (int i = tid; i < NB; i += blockDim.x) hist[i] = 0;
  __syncthreads();
  int stride = gridDim.x * blockDim.x;
  int g0 = blockIdx.x * blockDim.x + tid;
  for (int i = g0; i < n_tot; i += stride) {
    int d = (i < n_real) ? dstI[i] : (i - n_real);
    atomicAdd(&hist[d >> BSH], 1);
  }
  __syncthreads();
  for (int i = tid; i < NB; i += blockDim.x)
    base[i] = hist[i] ? atomicAdd(&bcur[i], hist[i]) : 0;
  __syncthreads();
  for (int i = tid; i < NB; i += blockDim.x) hist[i] = 0;
  __syncthreads();
  for (int i = g0; i < n_tot; i += stride) {
    int s, d;
    if (i < n_real) { s = srcI[i]; d = dstI[i]; }
    else { s = d = i - n_real; }
    int b = d >> BSH;
    int p = base[b] + atomicAdd(&hist[b], 1);
    bbuf[p] = (s << BSH) | (d & (BWID - 1));
  }
}

// ---- per-bucket: per-dst hist -> scan -> rowptr + csr scatter (L2-local) ----
__global__ void k_bbuild(const int* __restrict__ boff, const int* __restrict__ bbuf,
                         int* __restrict__ rowptr, int* __restrict__ csr, int N) {
  __shared__ int hist[BWID];
  __shared__ int sc[BWID];
  int b = blockIdx.x;
  int tid = threadIdx.x;  // 256
  int base_dst = b << BSH;
  int nd = min(BWID, N - base_dst);
  int s0 = boff[b], s1 = boff[b + 1];
  hist[tid] = 0;
  __syncthreads();
  for (int j = s0 + tid; j < s1; j += BWID)
    atomicAdd(&hist[bbuf[j] & (BWID - 1)], 1);
  __syncthreads();
  int v = hist[tid];
  sc[tid] = v;
  __syncthreads();
  for (int off = 1; off < BWID; off <<= 1) {
    int add = (tid >= off) ? sc[tid - off] : 0;
    __syncthreads();
    sc[tid] += add;
    __syncthreads();
  }
  int excl = sc[tid] - v;
  if (tid < nd) rowptr[base_dst + tid] = s0 + excl;
  __syncthreads();
  hist[tid] = excl;
  __syncthreads();
  for (int j = s0 + tid; j < s1; j += BWID) {
    int e = bbuf[j];
    int dl = e & (BWID - 1);
    int p = s0 + atomicAdd(&hist[dl], 1);
    csr[p] = e >> BSH;
  }
}

// ---- h = in @ W (fp16, as packed in slot 15) ; ad_ fp32 ----
__global__ void k_transform(const float* __restrict__ in, int ld_in,
                            const float* __restrict__ W,
                            const float* __restrict__ a_s,
                            const float* __restrict__ a_d,
                            half_t* __restrict__ hp,
                            float* __restrict__ ad_,
                            int n_nodes) {
  __shared__ float Ws[FDIM * FDIM];
  __shared__ float asv[FDIM], adv[FDIM];
  int tid = threadIdx.x;
  if (tid < FDIM * FDIM) Ws[tid] = W[tid];
  if (tid < FDIM) { asv[tid] = a_s[tid]; adv[tid] = a_d[tid]; }
  __syncthreads();
  int n = blockIdx.x * blockDim.x + tid;
  if (n >= n_nodes) return;
  float xin[FDIM];
#pragma unroll
  for (int j = 0; j < FDIM; ++j) xin[j] = in[n * ld_in + j];
  float sa = 0.f, da = 0.f;
  half_t hrow[FPAD];
#pragma unroll
  for (int o = 0; o < FDIM; ++o) {
    float acc = 0.f;
#pragma unroll
    for (int k = 0; k < FDIM; ++k) acc += xin[k] * Ws[k * FDIM + o];
    hrow[o] = (half_t)acc;
    sa += acc * asv[o];
    da += acc * adv[o];
  }
  hrow[FDIM] = (half_t)sa;
  ad_[n] = da;
  float4 w0, w1;
  __builtin_memcpy(&w0, &hrow[0], 16);
  __builtin_memcpy(&w1, &hrow[8], 16);
  float4* dst = (float4*)(hp + (size_t)n * FPAD);
  dst[0] = w0;
  dst[1] = w1;
}

// ---- fused GAT aggregate + FFN: branchless dual-state online softmax ----
__global__ void k_gat(const int* __restrict__ rowptr, const int* __restrict__ csr,
                      const half_t* __restrict__ hp, const float* __restrict__ ad_,
                      const float* __restrict__ cb, const float* __restrict__ fW,
                      const float* __restrict__ fb,
                      float* __restrict__ fout, int n_nodes, int do_relu) {
  __shared__ float Ws[FDIM * FDIM];
  __shared__ float cbv[FDIM], fbv[FDIM];
  __shared__ float aggT[16][16];
  int tid = threadIdx.x;
  if (tid < FDIM * FDIM) Ws[tid] = fW[tid];
  if (tid < FDIM) { cbv[tid] = cb[tid]; fbv[tid] = fb[tid]; }
  __syncthreads();
  int dl = tid >> 4;          // local dst 0..15
  int f  = tid & 15;          // feature lane 0..15 (lane 15 carries `as`)
  int d  = blockIdx.x * 16 + dl;
  float val = 0.f;
  if (d < n_nodes) {
    int rs = rowptr[d], re = rowptr[d + 1];
    float adv = ad_[d];
    float ma = -INFINITY, dena = 0.f, acca = 0.f;
    float mb = -INFINITY, denb = 0.f, accb = 0.f;
    int j = rs;
    for (; j + 1 < re; j += 2) {
      int s0 = csr[j], s1 = csr[j + 1];
      float hv0 = (float)hp[(size_t)s0 * FPAD + f];
      float hv1 = (float)hp[(size_t)s1 * FPAD + f];
      float e0 = leaky(__shfl(hv0, 15, 16) + adv);
      float e1 = leaky(__shfl(hv1, 15, 16) + adv);
      float m0 = fmaxf(ma, e0);
      float sc0 = __expf(ma - m0), w0 = __expf(e0 - m0);
      dena = dena * sc0 + w0; acca = acca * sc0 + hv0 * w0; ma = m0;
      float m1 = fmaxf(mb, e1);
      float sc1 = __expf(mb - m1), w1 = __expf(e1 - m1);
      denb = denb * sc1 + w1; accb = accb * sc1 + hv1 * w1; mb = m1;
    }
    if (j < re) {
      int s0 = csr[j];
      float hv0 = (float)hp[(size_t)s0 * FPAD + f];
      float e0 = leaky(__shfl(hv0, 15, 16) + adv);
      float m0 = fmaxf(ma, e0);
      float sc0 = __expf(ma - m0), w0 = __expf(e0 - m0);
      dena = dena * sc0 + w0; acca = acca * sc0 + hv0 * w0; ma = m0;
    }
    float m = fmaxf(ma, mb);
    float wa = __expf(ma - m), wb = __expf(mb - m);
    float den = dena * wa + denb * wb;
    float acc = acca * wa + accb * wb;
    val = acc / (den + 1e-16f);
  }
  aggT[dl][f] = (f < FDIM) ? (val + cbv[f]) : 0.f;
  __syncthreads();
  if (d < n_nodes) {
    int o = f;
    if (o < FDIM) {
      float acc2 = fbv[o];
#pragma unroll
      for (int k = 0; k < FDIM; ++k) acc2 += aggT[dl][k] * Ws[k * FDIM + o];
      if (do_relu) acc2 = fmaxf(acc2, 0.f);
      fout[d * FPAD + o] = acc2;
    } else {
      fout[d * FPAD + FDIM] = 0.f;
    }
  }
}

// ---- pooling: one block per graph (batch sorted), no atomics ----
__device__ __forceinline__ int lowerb(const int* __restrict__ a, int n, int key) {
  int lo = 0, hi = n;
  while (lo < hi) { int mid = (lo + hi) >> 1; if (a[mid] < key) lo = mid + 1; else hi = mid; }
  return lo;
}

__global__ void k_pool(const float* __restrict__ fout, const int* __restrict__ batch,
                       float* __restrict__ pooled, int n_nodes) {
  __shared__ float ss[256], sm[256];
  int g = blockIdx.x;
  int tid = threadIdx.x;
  int s = lowerb(batch, n_nodes, g);
  int e = lowerb(batch, n_nodes, g + 1);
  int f = tid & 15;
  float sum = 0.f, mx = -INFINITY;
  for (int n = s + (tid >> 4); n < e; n += 16) {
    float v = fout[n * FPAD + f];
    sum += v;
    mx = fmaxf(mx, v);
  }
  ss[tid] = sum; sm[tid] = mx;
  __syncthreads();
  for (int step = 128; step >= 16; step >>= 1) {
    if (tid < step) { ss[tid] += ss[tid + step]; sm[tid] = fmaxf(sm[tid], sm[tid + step]); }
    __syncthreads();
  }
  if (tid < FDIM) {
    float cnt = (float)(e - s);
    float sv = ss[tid];
    pooled[g * 45 + tid] = sv;
    pooled[g * 45 + 15 + tid] = sm[tid];
    pooled[g * 45 + 30 + tid] = sv / fmaxf(cnt, 1.f);
  }
}

// ---- small GEMM: C[i,j] = act(sum_k A[i,k]*B[k,j] + bias[j]) ----
__global__ void k_gemm(const float* __restrict__ A, const float* __restrict__ B,
                       const float* __restrict__ bias, float* __restrict__ C,
                       int K, int Nc, int act) {
  __shared__ float Arow[304];
  int i = blockIdx.x;
  for (int k = threadIdx.x; k < K; k += blockDim.x) Arow[k] = A[i * K + k];
  __syncthreads();
  for (int j = threadIdx.x; j < Nc; j += blockDim.x) {
    float acc = bias[j];
    for (int k = 0; k < K; ++k) acc += Arow[k] * B[k * Nc + j];
    if (act == 1) acc = fmaxf(acc, 0.f);
    else if (act == 2) acc = 1.f / (1.f + expf(-acc));
    C[i * Nc + j] = acc;
  }
}

// ---- head ----
__global__ void k_final(const float* __restrict__ pooled, const float* __restrict__ xann,
                        const float* __restrict__ m1W, const float* __restrict__ m1b,
                        const float* __restrict__ m2W, const float* __restrict__ m2b,
                        float* __restrict__ out) {
  __shared__ float z[90];
  __shared__ float z2[90];
  int g = blockIdx.x;
  int t = threadIdx.x;  // 128
  if (t < 45) z[t] = pooled[g * 45 + t];
  else if (t < 90) z[t] = xann[g * 45 + (t - 45)];
  __syncthreads();
  if (t < 90) {
    float acc = m1b[t];
    for (int k = 0; k < 90; ++k) acc += z[k] * m1W[k * 90 + t];
    z2[t] = fmaxf(acc, 0.f);
  }
  __syncthreads();
  if (t == 0) {
    float acc = m2b[0];
    for (int k = 0; k < 90; ++k) acc += z2[k] * m2W[k];
    out[g] = 1.f / (1.f + expf(-acc));
  }
}

extern "C" void kernel_launch(void* const* d_in, const int* in_sizes, int n_in,
                              void* d_out, int out_size, void* d_ws, size_t ws_size,
                              hipStream_t stream) {
  const float* x   = (const float*)d_in[0];
  const int* ei    = (const int*)d_in[1];
  const int* batch = (const int*)d_in[2];
  const float* xA  = (const float*)d_in[3];

  const int N = in_sizes[0] / FDIM;
  const int E = in_sizes[1] / 2;
  const int G = in_sizes[3] / 300;
  const int ET = E + N;
  const int NB = (N + BWID - 1) >> BSH;   // dst buckets (<=512 for N<=131072)

  const int* srcI = ei;
  const int* dstI = ei + E;

  // ---- workspace layout (4-byte words) ----
  // bbuf (build phase) overlays hp/fout/ad_ (layer phase) — never live together.
  float* ws = (float*)d_ws;
  size_t layerW = (size_t)25 * N;          // hp(8N) + fout(16N) + ad_(N)
  size_t uSize = layerW > (size_t)ET ? layerW : (size_t)ET;
  size_t off = 0;
  int*    bbuf = (int*)(ws + off);
  half_t* hp   = (half_t*)(ws + off);
  float*  fout = ws + off + (size_t)8 * N;
  float*  ad_  = ws + off + (size_t)24 * N;
  off += uSize;
  int*   rowptr = (int*)(ws + off); off += N + 1;
  int*   csr    = (int*)(ws + off); off += (size_t)ET;
  int*   bcnt   = (int*)(ws + off); off += 516;
  int*   boff   = (int*)(ws + off); off += 516;
  int*   bcur   = (int*)(ws + off); off += 516;
  float* pooled = ws + off; off += (size_t)G * 45;
  float* a1     = ws + off; off += (size_t)G * 300;
  float* a2     = ws + off; off += (size_t)G * 300;
  float* xann   = ws + off; off += (size_t)G * 45;

  const int B = 256;
  const int gN = (N + B - 1) / B;

  // ---- bucketed CSR build ----
  k_zero<<<(NB + B - 1) / B, B, 0, stream>>>(bcnt, NB);
  k_bhist<<<256, B, 0, stream>>>(dstI, bcnt, ET, E, NB);
  k_bscan<<<1, 512, 0, stream>>>(bcnt, boff, bcur, rowptr, NB, N, ET);
  k_bpart<<<256, B, 0, stream>>>(srcI, dstI, bcur, bbuf, ET, E, NB);
  k_bbuild<<<NB, BWID, 0, stream>>>(boff, bbuf, rowptr, csr, N);

  // ---- 3 GAT layers ----
  const float* in_ptr = x;
  int ld_in = FDIM;
  const int gGat = (N + 15) / 16;
  for (int l = 0; l < 3; ++l) {
    const float* cW  = (const float*)d_in[4 + 6 * l];
    const float* cas = (const float*)d_in[5 + 6 * l];
    const float* cad = (const float*)d_in[6 + 6 * l];
    const float* cb  = (const float*)d_in[7 + 6 * l];
    const float* fW  = (const float*)d_in[8 + 6 * l];
    const float* fb  = (const float*)d_in[9 + 6 * l];

    k_transform<<<gN, B, 0, stream>>>(in_ptr, ld_in, cW, cas, cad, hp, ad_, N);
    k_gat<<<gGat, B, 0, stream>>>(rowptr, csr, hp, ad_, cb, fW, fb, fout,
                                  N, (l < 2) ? 1 : 0);
    in_ptr = fout;
    ld_in = FPAD;
  }

  // ---- pooling ----
  k_pool<<<G, B, 0, stream>>>(fout, batch, pooled, N);

  // ---- annotation MLP ----
  const float* m1W = (const float*)d_in[22];
  const float* m1b = (const float*)d_in[23];
  const float* aW1 = (const float*)d_in[24];
  const float* ab1 = (const float*)d_in[25];
  const float* aW2 = (const float*)d_in[26];
  const float* ab2 = (const float*)d_in[27];
  const float* aW3 = (const float*)d_in[28];
  const float* ab3 = (const float*)d_in[29];
  const float* aW4 = (const float*)d_in[30];
  const float* ab4 = (const float*)d_in[31];
  const float* m2W = (const float*)d_in[32];
  const float* m2b = (const float*)d_in[33];

  k_gemm<<<G, 320, 0, stream>>>(xA, aW1, ab1, a1, 300, 300, 1);
  k_gemm<<<G, 320, 0, stream>>>(a1, aW2, ab2, a2, 300, 300, 1);
  k_gemm<<<G, 320, 0, stream>>>(a2, aW3, ab3, a1, 300, 300, 2);
  k_gemm<<<G, 320, 0, stream>>>(a1, aW4, ab4, xann, 300, 45, 0);

  // ---- head ----
  k_final<<<G, 128, 0, stream>>>(pooled, xann, m1W, m1b, m2W, m2b, (float*)d_out);
}